// Round 15
// baseline (1023.968 us; speedup 1.0000x reference)
//
#include <hip/hip_runtime.h>
#include <hip/hip_bf16.h>

// B=1 T=64 W=88 HP=48 F0=53 HL=12 GATES=48 NU=24 NH=4 HD=6 K=25
// All float tensors are float32; condition is int32.
#define NPIX (64*88)          // 5632
#define NSEQ 88
#define TT 64
#define F0 53
#define GATES 48

typedef __hip_bfloat16 bf16;

__device__ __forceinline__ float frcp(float x){ return __builtin_amdgcn_rcpf(x); }
__device__ __forceinline__ float blo(unsigned u){ return __uint_as_float(u<<16); }
__device__ __forceinline__ float bhi(unsigned u){ return __uint_as_float(u & 0xffff0000u); }

// ============ D1: whole LSTM stack + qkv. 88 blocks x 1024 threads =========
// Lane mapping: t = lane for all GEMV phases -> weight reads are wave-uniform
// (LDS broadcast), x reads conflict-free. gbuf stride 49, y0/y1 stride 25.
__global__ __launch_bounds__(1024) void k_core(
    const float* __restrict__ feat, const int* __restrict__ cond,
    const float* __restrict__ mask, const float* __restrict__ emb,
    const float* __restrict__ wih0, const float* __restrict__ whh0,
    const float* __restrict__ bih0, const float* __restrict__ bhh0,
    const float* __restrict__ wih1, const float* __restrict__ whh1,
    const float* __restrict__ bih1, const float* __restrict__ bhh1,
    const float* __restrict__ qkv_w, const float* __restrict__ qkv_b,
    float* __restrict__ q, bf16* __restrict__ kh, bf16* __restrict__ vh){
  int n = (blockIdx.x & 7)*11 + (blockIdx.x >> 3);   // XCD-aware remap
  int tid = threadIdx.x;
  int wave = tid >> 6; int lane = tid & 63;
  __shared__ float smem[15200];
  float* gbuf = smem;               // 2*64*49 = 6272, whole lifetime
  float* sx   = smem + 6272;        // 3392  (phase A)
  float* sw0  = smem + 9664;        // 5088  (phase A)
  float* w1   = smem + 6272;        // 2400  (phase B+) aliases sx
  float* sqkv = smem + 8672;        // 1800  (phase B+)
  float* y0   = smem + 10472;       // 64*25 = 1600
  float* y1   = smem + 12072;       // 1600
  float* bsum = smem + 15008;       // 192

  // ---- Phase A: stage x-tile, wih0, bias sums ----
  for (int idx = tid; idx < 2*GATES*F0; idx += 1024) sw0[idx] = wih0[idx];
  for (int idx = tid; idx < TT*F0; idx += 1024){
    int t = idx / F0, f = idx - t*F0;
    float v;
    if (f < 48)      v = feat[(t*48 + f)*88 + n];
    else if (f < 52) v = emb[cond[t*88+n]*4 + (f-48)];
    else             v = mask[t*88+n];
    sx[idx] = v;
  }
  if (tid < 96)       bsum[tid] = bih0[tid] + bhh0[tid];
  else if (tid < 192) bsum[tid] = bih1[tid-96] + bhh1[tid-96];
  __syncthreads();

  // ---- gates layer 0: t=lane, 6 j per thread, weights broadcast ----------
  {
    int d = tid >> 9; int jg = (tid >> 6) & 7; int t = lane;
    int j0 = jg*6;
    const float* xr = sx + t*F0;
    const float* wr = sw0 + (d*GATES + j0)*F0;
    float a0 = bsum[d*GATES+j0+0], a1 = bsum[d*GATES+j0+1];
    float a2 = bsum[d*GATES+j0+2], a3 = bsum[d*GATES+j0+3];
    float a4 = bsum[d*GATES+j0+4], a5 = bsum[d*GATES+j0+5];
    for (int f=0; f<F0; ++f){
      float xv = xr[f];
      a0 += xv*wr[f];
      a1 += xv*wr[F0+f];
      a2 += xv*wr[2*F0+f];
      a3 += xv*wr[3*F0+f];
      a4 += xv*wr[4*F0+f];
      a5 += xv*wr[5*F0+f];
    }
    float* gw = gbuf + (d*TT + t)*49 + j0;
    gw[0]=a0; gw[1]=a1; gw[2]=a2; gw[3]=a3; gw[4]=a4; gw[5]=a5;
  }
  __syncthreads();

  // ---- Phase B: rec0 (waves 0,1); waves >=2 stage w1 + sqkv -------------
  if (wave >= 2){
    for (int idx = tid-128; idx < 2*GATES*24; idx += 896){
      int row = idx / 24, f = idx - row*24;
      w1[row*25 + f] = wih1[idx];
    }
    for (int idx = tid-128; idx < 72*24; idx += 896){
      int row = idx / 24, f = idx - row*24;
      sqkv[row*25 + f] = qkv_w[idx];
    }
  } else {
    int d = wave;
    int j = (lane < GATES) ? lane : (lane - GATES);
    int u = j % 12; int grp = j / 12;          // 0:i 1:f 2:g 3:o
    float w[12];
    const float* wb = whh0 + (d*GATES + j)*12;
    #pragma unroll
    for (int m=0;m<12;++m) w[m] = wb[m];
    float negs  = (grp==2) ? -2.f : -1.f;      // tanh(x)=2*sigm(2x)-1
    float amul  = (grp==2) ?  2.f :  1.f;
    float aadd  = (grp==2) ? -1.f :  0.f;
    const float* gb = gbuf + d*TT*49 + j;
    float hval = 0.f, cval = 0.f;
    int t0 = d ? (TT-1) : 0;
    float gnext = gb[t0*49];
    for (int s=0;s<TT;++s){
      int t = d ? (TT-1-s) : s;
      float gg = gnext;
      int tn = d ? max(TT-2-s,0) : min(s+1,TT-1);
      gnext = gb[tn*49];
      float h0=__shfl(hval,0), h1=__shfl(hval,1), h2=__shfl(hval,2);
      float h3=__shfl(hval,3), h4=__shfl(hval,4), h5=__shfl(hval,5);
      float h6=__shfl(hval,6), h7=__shfl(hval,7), h8=__shfl(hval,8);
      float h9=__shfl(hval,9), h10=__shfl(hval,10), h11=__shfl(hval,11);
      float a0 = gg + h0*w[0] + h4*w[4] + h8*w[8];
      float a1 = h1*w[1] + h5*w[5] + h9*w[9];
      float a2 = h2*w[2] + h6*w[6] + h10*w[10];
      float a3 = h3*w[3] + h7*w[7] + h11*w[11];
      float dot = (a0+a1)+(a2+a3);
      float act = amul*frcp(1.f + __expf(negs*dot)) + aadd;
      float ai = __shfl(act, u);
      float af = __shfl(act, u+12);
      float ag = __shfl(act, u+24);
      float ao = __shfl(act, u+36);
      float cn = af*cval + ai*ag;
      float th = 2.f*frcp(1.f + __expf(-2.f*cn)) - 1.f;
      hval = ao*th; cval = cn;
      if (lane < 12) y0[t*25 + d*12 + lane] = hval;
    }
  }
  __syncthreads();

  // ---- gates layer 1: t=lane, 6 j per thread -----------------------------
  {
    int d = tid >> 9; int jg = (tid >> 6) & 7; int t = lane;
    int j0 = jg*6;
    const float* xr = y0 + t*25;
    const float* wr = w1 + (d*GATES + j0)*25;
    float a0 = bsum[96+d*GATES+j0+0], a1 = bsum[96+d*GATES+j0+1];
    float a2 = bsum[96+d*GATES+j0+2], a3 = bsum[96+d*GATES+j0+3];
    float a4 = bsum[96+d*GATES+j0+4], a5 = bsum[96+d*GATES+j0+5];
    #pragma unroll
    for (int c=0; c<24; ++c){
      float xv = xr[c];
      a0 += xv*wr[c];
      a1 += xv*wr[25+c];
      a2 += xv*wr[50+c];
      a3 += xv*wr[75+c];
      a4 += xv*wr[100+c];
      a5 += xv*wr[125+c];
    }
    float* gw = gbuf + (d*TT + t)*49 + j0;
    gw[0]=a0; gw[1]=a1; gw[2]=a2; gw[3]=a3; gw[4]=a4; gw[5]=a5;
  }
  __syncthreads();

  // ---- rec1 (waves 0,1) --------------------------------------------------
  if (wave < 2){
    int d = wave;
    int j = (lane < GATES) ? lane : (lane - GATES);
    int u = j % 12; int grp = j / 12;
    float w[12];
    const float* wb = whh1 + (d*GATES + j)*12;
    #pragma unroll
    for (int m=0;m<12;++m) w[m] = wb[m];
    float negs  = (grp==2) ? -2.f : -1.f;
    float amul  = (grp==2) ?  2.f :  1.f;
    float aadd  = (grp==2) ? -1.f :  0.f;
    const float* gb = gbuf + d*TT*49 + j;
    float hval = 0.f, cval = 0.f;
    int t0 = d ? (TT-1) : 0;
    float gnext = gb[t0*49];
    for (int s=0;s<TT;++s){
      int t = d ? (TT-1-s) : s;
      float gg = gnext;
      int tn = d ? max(TT-2-s,0) : min(s+1,TT-1);
      gnext = gb[tn*49];
      float h0=__shfl(hval,0), h1=__shfl(hval,1), h2=__shfl(hval,2);
      float h3=__shfl(hval,3), h4=__shfl(hval,4), h5=__shfl(hval,5);
      float h6=__shfl(hval,6), h7=__shfl(hval,7), h8=__shfl(hval,8);
      float h9=__shfl(hval,9), h10=__shfl(hval,10), h11=__shfl(hval,11);
      float a0 = gg + h0*w[0] + h4*w[4] + h8*w[8];
      float a1 = h1*w[1] + h5*w[5] + h9*w[9];
      float a2 = h2*w[2] + h6*w[6] + h10*w[10];
      float a3 = h3*w[3] + h7*w[7] + h11*w[11];
      float dot = (a0+a1)+(a2+a3);
      float act = amul*frcp(1.f + __expf(negs*dot)) + aadd;
      float ai = __shfl(act, u);
      float af = __shfl(act, u+12);
      float ag = __shfl(act, u+24);
      float ao = __shfl(act, u+36);
      float cn = af*cval + ai*ag;
      float th = 2.f*frcp(1.f + __expf(-2.f*cn)) - 1.f;
      hval = ao*th; cval = cn;
      if (lane < 12) y1[t*25 + d*12 + lane] = hval;
    }
  }
  __syncthreads();

  // ---- qkv: t=lane, 6 rows per thread (768 threads active) ---------------
  if (tid < 768){
    int rg = tid >> 6; int t = lane;
    int gq0 = rg*6;
    int p = t*88 + n;
    const float* xr = y1 + t*25;
    #pragma unroll
    for (int k=0; k<6; ++k){
      int gq = gq0 + k;
      const float* wr = sqkv + gq*25;
      float acc = qkv_b[gq];
      #pragma unroll
      for (int c=0; c<24; ++c) acc += xr[c]*wr[c];
      int s = gq/24, rem = gq - s*24;
      if (s==0) q[p*24+rem] = acc*0.4082482904638631f;   // 1/sqrt(HD)
      else {
        int hh = rem/6, pos = rem - hh*6;
        bf16* dst = (s==1) ? kh : vh;
        dst[((size_t)hh*NPIX + p)*8 + pos] = __float2bfloat16(acc);
      }
    }
  }
}

// ============ attn layer 1: block = (head, 4x2 tile), bf16 LDS tiles =======
__global__ __launch_bounds__(512) void k_attn(
    const float* __restrict__ q, const bf16* __restrict__ kh,
    const bf16* __restrict__ vh, const float* __restrict__ rpb,
    float* __restrict__ ao){
  int b = blockIdx.x;
  int h = b / 704; int rem = b - h*704;
  int ti = rem / 44, tj = rem - ti*44;
  int i0 = ti*4, j0 = tj*2;
  int tid = threadIdx.x;
  int w = tid >> 6; int lane = tid & 63;
  int osi = min(max(i0-12,0),39);
  int osj = min(max(j0-12,0),63);

  __shared__ unsigned kt[728*5];    // row stride 5 uints (coprime w/ 32 banks)
  __shared__ unsigned vt[728*5];
  const uint4* kg = (const uint4*)(kh + (size_t)h*NPIX*8);
  const uint4* vg = (const uint4*)(vh + (size_t)h*NPIX*8);
  for (int idx = tid; idx < 728; idx += 512){
    int a = idx / 26, cc = idx - a*26;
    int gi = min(osi + a, 63), gj = min(osj + cc, 87);
    int src = gi*88 + gj;
    uint4 kr = kg[src];
    uint4 vr = vg[src];
    int o = idx*5;
    kt[o] = kr.x; kt[o+1] = kr.y; kt[o+2] = kr.z;
    vt[o] = vr.x; vt[o+1] = vr.y; vt[o+2] = vr.z;
  }
  __syncthreads();

  int pi = i0 + (w>>1), pj = j0 + (w&1);
  int p = pi*88 + pj;
  int dsi = min(max(pi-12,0),39) - osi;
  int dsj = min(max(pj-12,0),63) - osj;
  int rbi = osi + dsi - pi + 24;
  int rbj = osj + dsj - pj + 24;

  float qv[6];
  #pragma unroll
  for (int d=0; d<6; ++d) qv[d] = q[p*24 + h*6 + d];

  float lgv[10]; int rof[10];
  float lmax = -1e30f;
  #pragma unroll
  for (int it=0; it<10; ++it){
    int nb = lane + it*64;
    bool valid = nb < 625;
    int nbc = valid ? nb : 624;
    int a = nbc/25, cc = nbc - a*25;
    int r5 = ((a+dsi)*26 + (cc+dsj))*5;
    rof[it] = r5;
    unsigned k0 = kt[r5], k1 = kt[r5+1], k2 = kt[r5+2];
    float lg = qv[0]*blo(k0)+qv[1]*bhi(k0)+qv[2]*blo(k1)
             + qv[3]*bhi(k1)+qv[4]*blo(k2)+qv[5]*bhi(k2);
    lg += rpb[(h*49 + (a + rbi))*49 + (cc + rbj)];
    lg = valid ? lg : -1e30f;
    lgv[it] = lg;
    lmax = fmaxf(lmax, lg);
  }
  #pragma unroll
  for (int off=32; off; off>>=1) lmax = fmaxf(lmax, __shfl_xor(lmax, off));
  float lsum = 0.f;
  #pragma unroll
  for (int it=0; it<10; ++it){
    float pe = __expf(lgv[it]-lmax);
    lgv[it] = pe; lsum += pe;
  }
  #pragma unroll
  for (int off=32; off; off>>=1) lsum += __shfl_xor(lsum, off);
  float acc[6] = {0,0,0,0,0,0};
  #pragma unroll
  for (int it=0; it<10; ++it){
    int r5 = rof[it];
    unsigned v0 = vt[r5], v1 = vt[r5+1], v2 = vt[r5+2];
    float pe = lgv[it];
    acc[0] += pe*blo(v0); acc[1] += pe*bhi(v0);
    acc[2] += pe*blo(v1); acc[3] += pe*bhi(v1);
    acc[4] += pe*blo(v2); acc[5] += pe*bhi(v2);
  }
  #pragma unroll
  for (int d=0; d<6; ++d){
    #pragma unroll
    for (int off=32; off; off>>=1) acc[d] += __shfl_xor(acc[d], off);
  }
  if (lane == 0){
    float inv = frcp(lsum);
    #pragma unroll
    for (int d=0; d<6; ++d) ao[p*24 + h*6 + d] = acc[d]*inv;
  }
}

// ============ attn layer 2 with fused proj+qkv prefix (window recompute) ===
// Computes proj->k/v (fp32) for its 28x26 window from layer-1 AO, q for its
// own 8 pixels, then the attention phase from LDS. Writes ao2.
__global__ __launch_bounds__(512) void k_attn2(
    const float* __restrict__ ao,
    const float* __restrict__ pw, const float* __restrict__ pb,
    const float* __restrict__ qkv_w, const float* __restrict__ qkv_b,
    const float* __restrict__ rpb, float* __restrict__ ao2){
  int b = blockIdx.x;
  int h = b / 704; int rem = b - h*704;
  int ti = rem / 44, tj = rem - ti*44;
  int i0 = ti*4, j0 = tj*2;
  int tid = threadIdx.x;
  int w = tid >> 6; int lane = tid & 63;
  int osi = min(max(i0-12,0),39);
  int osj = min(max(j0-12,0),63);

  __shared__ float kt[728*7];       // fp32, stride 7 (coprime w/ 32 banks)
  __shared__ float vt[728*7];
  __shared__ float spw[24*25];
  __shared__ float sqw[18*25];      // q(0-5), k(6-11), v(12-17) rows of head h
  __shared__ float sb[48];          // pb(0-23), q/k/v biases (24-41)
  __shared__ float sq[8*8];

  for (int idx = tid; idx < 24*24; idx += 512){
    int o = idx/24, c = idx - o*24;
    spw[o*25+c] = pw[idx];
  }
  for (int idx = tid; idx < 18*24; idx += 512){
    int g = idx/24, c = idx - g*24;
    int s = g/6, r = g - s*6;
    sqw[g*25+c] = qkv_w[(s*24 + h*6 + r)*24 + c];
  }
  if (tid < 24) sb[tid] = pb[tid];
  else if (tid < 42){
    int g = tid-24; int s = g/6, r = g - s*6;
    sb[24+g] = qkv_b[s*24 + h*6 + r];
  }
  __syncthreads();

  // ---- prefix: proj + k/v (+own q) for window pixels ----
  for (int idx = tid; idx < 728; idx += 512){
    int a = idx / 26, cc = idx - a*26;
    int gir = osi + a, gjr = osj + cc;
    int gi = min(gir, 63), gj = min(gjr, 87);
    const float* ar = ao + (gi*88+gj)*24;
    float arow[24];
    #pragma unroll
    for (int u=0;u<6;++u){
      float4 t4 = ((const float4*)ar)[u];
      arow[4*u]=t4.x; arow[4*u+1]=t4.y; arow[4*u+2]=t4.z; arow[4*u+3]=t4.w;
    }
    float xr[24];
    #pragma unroll
    for (int o=0;o<24;++o){
      float acc2 = sb[o];
      const float* wr = spw + o*25;
      #pragma unroll
      for (int c=0;c<24;++c) acc2 += arow[c]*wr[c];
      xr[o] = acc2;
    }
    #pragma unroll
    for (int r=0;r<6;++r){
      float ka = sb[30+r], va = sb[36+r];
      const float* wk = sqw + (6+r)*25;
      const float* wv = sqw + (12+r)*25;
      #pragma unroll
      for (int c=0;c<24;++c){ ka += xr[c]*wk[c]; va += xr[c]*wv[c]; }
      kt[idx*7+r] = ka;
      vt[idx*7+r] = va;
    }
    if (gir == gi && gjr == gj &&
        gir >= i0 && gir < i0+4 && gjr >= j0 && gjr < j0+2){
      int pl = (gir-i0)*2 + (gjr-j0);
      #pragma unroll
      for (int r=0;r<6;++r){
        float qa = sb[24+r];
        const float* wq = sqw + r*25;
        #pragma unroll
        for (int c=0;c<24;++c) qa += xr[c]*wq[c];
        sq[pl*8+r] = qa*0.4082482904638631f;
      }
    }
  }
  __syncthreads();

  // ---- attention phase ----
  int pi = i0 + (w>>1), pj = j0 + (w&1);
  int p = pi*88 + pj;
  int dsi = min(max(pi-12,0),39) - osi;
  int dsj = min(max(pj-12,0),63) - osj;
  int rbi = osi + dsi - pi + 24;
  int rbj = osj + dsj - pj + 24;

  float qv[6];
  #pragma unroll
  for (int d=0; d<6; ++d) qv[d] = sq[w*8+d];

  float lgv[10]; int rof[10];
  float lmax = -1e30f;
  #pragma unroll
  for (int it=0; it<10; ++it){
    int nb = lane + it*64;
    bool valid = nb < 625;
    int nbc = valid ? nb : 624;
    int a = nbc/25, cc = nbc - a*25;
    int r7 = ((a+dsi)*26 + (cc+dsj))*7;
    rof[it] = r7;
    float lg = qv[0]*kt[r7]+qv[1]*kt[r7+1]+qv[2]*kt[r7+2]
             + qv[3]*kt[r7+3]+qv[4]*kt[r7+4]+qv[5]*kt[r7+5];
    lg += rpb[(h*49 + (a + rbi))*49 + (cc + rbj)];
    lg = valid ? lg : -1e30f;
    lgv[it] = lg;
    lmax = fmaxf(lmax, lg);
  }
  #pragma unroll
  for (int off=32; off; off>>=1) lmax = fmaxf(lmax, __shfl_xor(lmax, off));
  float lsum = 0.f;
  #pragma unroll
  for (int it=0; it<10; ++it){
    float pe = __expf(lgv[it]-lmax);
    lgv[it] = pe; lsum += pe;
  }
  #pragma unroll
  for (int off=32; off; off>>=1) lsum += __shfl_xor(lsum, off);
  float acc[6] = {0,0,0,0,0,0};
  #pragma unroll
  for (int it=0; it<10; ++it){
    int r7 = rof[it];
    float pe = lgv[it];
    acc[0] += pe*vt[r7];   acc[1] += pe*vt[r7+1];
    acc[2] += pe*vt[r7+2]; acc[3] += pe*vt[r7+3];
    acc[4] += pe*vt[r7+4]; acc[5] += pe*vt[r7+5];
  }
  #pragma unroll
  for (int d=0; d<6; ++d){
    #pragma unroll
    for (int off=32; off; off>>=1) acc[d] += __shfl_xor(acc[d], off);
  }
  if (lane == 0){
    float inv = frcp(lsum);
    #pragma unroll
    for (int d=0; d<6; ++d) ao2[p*24 + h*6 + d] = acc[d]*inv;
  }
}

// ============ proj + final 24->5 head ======================================
__global__ __launch_bounds__(64) void k_proj_out(const float* __restrict__ ain,
    const float* __restrict__ pw, const float* __restrict__ pb,
    const float* __restrict__ ow, const float* __restrict__ ob,
    float* __restrict__ out){
  int p = blockIdx.x; int tid = threadIdx.x;
  __shared__ float arow[24];
  __shared__ float xrow[24];
  if (tid < 24) arow[tid] = ain[p*24+tid];
  __syncthreads();
  if (tid < 24){
    float a2 = pb[tid];
    const float* wr = pw + tid*24;
    #pragma unroll
    for (int c=0;c<24;++c) a2 += arow[c]*wr[c];
    xrow[tid] = a2;
  }
  __syncthreads();
  if (tid < 5){
    float a2 = ob[tid];
    const float* wr = ow + tid*24;
    #pragma unroll
    for (int c=0;c<24;++c) a2 += xrow[c]*wr[c];
    out[p*5+tid] = a2;
  }
}

extern "C" void kernel_launch(void* const* d_in, const int* in_sizes, int n_in,
                              void* d_out, int out_size, void* d_ws, size_t ws_size,
                              hipStream_t stream) {
  const float* feat    = (const float*)d_in[0];
  const int*   cond    = (const int*)  d_in[1];
  const float* mask    = (const float*)d_in[2];
  const float* emb     = (const float*)d_in[3];
  const float* w_ih_l0 = (const float*)d_in[4];
  const float* w_hh_l0 = (const float*)d_in[5];
  const float* b_ih_l0 = (const float*)d_in[6];
  const float* b_hh_l0 = (const float*)d_in[7];
  const float* w_ih_l1 = (const float*)d_in[8];
  const float* w_hh_l1 = (const float*)d_in[9];
  const float* b_ih_l1 = (const float*)d_in[10];
  const float* b_hh_l1 = (const float*)d_in[11];
  const float* qkv_w   = (const float*)d_in[12];
  const float* qkv_b   = (const float*)d_in[13];
  const float* rpb     = (const float*)d_in[14];
  const float* proj_w  = (const float*)d_in[15];
  const float* proj_b  = (const float*)d_in[16];
  const float* out_w   = (const float*)d_in[17];
  const float* out_b   = (const float*)d_in[18];
  float* out = (float*)d_out;

  float* ws  = (float*)d_ws;
  float* Q1  = ws;                    // 135168 floats
  float* AO  = Q1 + 135168;           // 135168 (layer-1 attn out)
  float* AO2 = AO + 135168;           // 135168 (layer-2 attn out)
  bf16*  KH1 = (bf16*)(AO2 + 135168); // 180224 halves each
  bf16*  VH1 = KH1 + 180224;

  k_core<<<NSEQ, 1024, 0, stream>>>(
      feat, cond, mask, emb,
      w_ih_l0, w_hh_l0, b_ih_l0, b_hh_l0,
      w_ih_l1, w_hh_l1, b_ih_l1, b_hh_l1,
      qkv_w, qkv_b, Q1, KH1, VH1);

  k_attn<<<4*16*44, 512, 0, stream>>>(Q1, KH1, VH1, rpb, AO);

  k_attn2<<<4*16*44, 512, 0, stream>>>(AO, proj_w, proj_b, qkv_w, qkv_b,
                                       rpb, AO2);

  k_proj_out<<<NPIX, 64, 0, stream>>>(AO2, proj_w, proj_b, out_w, out_b, out);
}

// Round 16
// 204.593 us; speedup vs baseline: 5.0049x; 5.0049x over previous
//
#include <hip/hip_runtime.h>
#include <hip/hip_bf16.h>

// B=1 T=64 W=88 HP=48 F0=53 HL=12 GATES=48 NU=24 NH=4 HD=6 K=25
// All float tensors are float32; condition is int32.
#define NPIX (64*88)          // 5632
#define NSEQ 88
#define TT 64
#define F0 53
#define GATES 48

typedef __hip_bfloat16 bf16;

__device__ __forceinline__ float frcp(float x){ return __builtin_amdgcn_rcpf(x); }
__device__ __forceinline__ float blo(unsigned u){ return __uint_as_float(u<<16); }
__device__ __forceinline__ float bhi(unsigned u){ return __uint_as_float(u & 0xffff0000u); }

// unpack first 6 bf16 of a 16B row (uint4) to fp32
__device__ __forceinline__ void unpack6(uint4 r, float* f){
  f[0] = __uint_as_float(r.x << 16);
  f[1] = __uint_as_float(r.x & 0xffff0000u);
  f[2] = __uint_as_float(r.y << 16);
  f[3] = __uint_as_float(r.y & 0xffff0000u);
  f[4] = __uint_as_float(r.z << 16);
  f[5] = __uint_as_float(r.z & 0xffff0000u);
}

// ============ D1: whole LSTM stack + qkv. 88 blocks x 1024 threads =========
// (R14 exact — measured 56 us)
__global__ __launch_bounds__(1024) void k_core(
    const float* __restrict__ feat, const int* __restrict__ cond,
    const float* __restrict__ mask, const float* __restrict__ emb,
    const float* __restrict__ wih0, const float* __restrict__ whh0,
    const float* __restrict__ bih0, const float* __restrict__ bhh0,
    const float* __restrict__ wih1, const float* __restrict__ whh1,
    const float* __restrict__ bih1, const float* __restrict__ bhh1,
    const float* __restrict__ qkv_w, const float* __restrict__ qkv_b,
    float* __restrict__ q, bf16* __restrict__ kh, bf16* __restrict__ vh){
  int n = (blockIdx.x & 7)*11 + (blockIdx.x >> 3);   // XCD-aware remap
  int tid = threadIdx.x;
  int wave = tid >> 6; int lane = tid & 63;
  __shared__ float smem[14816];
  float* gbuf = smem;               // 6144 floats, whole lifetime
  float* sx   = smem + 6144;        // 3392  (phase A)
  float* sw0  = smem + 6144+3392;   // 5088  (phase A)
  float* w1   = smem + 6144;        // 2400  (phase B+) aliases sx
  float* sqkv = smem + 6144+2400;   // 1800  (phase B+)
  float* y0   = smem + 6144+4200;   // 1536
  float* y1   = smem + 6144+5736;   // 1536
  float* bsum = smem + 14624;       // 192

  for (int idx = tid; idx < 2*GATES*F0; idx += 1024) sw0[idx] = wih0[idx];
  for (int idx = tid; idx < TT*F0; idx += 1024){
    int t = idx / F0, f = idx - t*F0;
    float v;
    if (f < 48)      v = feat[(t*48 + f)*88 + n];
    else if (f < 52) v = emb[cond[t*88+n]*4 + (f-48)];
    else             v = mask[t*88+n];
    sx[idx] = v;
  }
  if (tid < 96)       bsum[tid] = bih0[tid] + bhh0[tid];
  else if (tid < 192) bsum[tid] = bih1[tid-96] + bhh1[tid-96];
  __syncthreads();

  #pragma unroll
  for (int r = 0; r < 6; ++r){
    int row = tid + r*1024;
    int d = row / 3072; int rem = row - d*3072;
    int t = rem / 48; int j = rem - t*48;
    const float* xr = sx + t*F0;
    const float* wr = sw0 + (d*GATES + j)*F0;
    float a0=0.f, a1=0.f, a2=0.f, a3=0.f;
    #pragma unroll
    for (int f=0; f<52; f+=4){
      a0 += xr[f  ]*wr[f  ];
      a1 += xr[f+1]*wr[f+1];
      a2 += xr[f+2]*wr[f+2];
      a3 += xr[f+3]*wr[f+3];
    }
    gbuf[(d*TT + t)*GATES + j] = bsum[d*GATES+j] + xr[52]*wr[52] + ((a0+a1)+(a2+a3));
  }
  __syncthreads();

  if (wave >= 2){
    for (int idx = tid-128; idx < 2*GATES*24; idx += 896){
      int row = idx / 24, f = idx - row*24;
      w1[row*25 + f] = wih1[idx];
    }
    for (int idx = tid-128; idx < 72*24; idx += 896){
      int row = idx / 24, f = idx - row*24;
      sqkv[row*25 + f] = qkv_w[idx];
    }
  } else {
    int d = wave;
    int j = (lane < GATES) ? lane : (lane - GATES);
    int u = j % 12; int grp = j / 12;          // 0:i 1:f 2:g 3:o
    float w[12];
    const float* wb = whh0 + (d*GATES + j)*12;
    #pragma unroll
    for (int m=0;m<12;++m) w[m] = wb[m];
    float negs  = (grp==2) ? -2.f : -1.f;      // tanh(x)=2*sigm(2x)-1
    float amul  = (grp==2) ?  2.f :  1.f;
    float aadd  = (grp==2) ? -1.f :  0.f;
    const float* gb = gbuf + d*TT*GATES + j;
    float hval = 0.f, cval = 0.f;
    int t0 = d ? (TT-1) : 0;
    float gnext = gb[t0*GATES];
    for (int s=0;s<TT;++s){
      int t = d ? (TT-1-s) : s;
      float gg = gnext;
      int tn = d ? max(TT-2-s,0) : min(s+1,TT-1);
      gnext = gb[tn*GATES];
      float h0=__shfl(hval,0), h1=__shfl(hval,1), h2=__shfl(hval,2);
      float h3=__shfl(hval,3), h4=__shfl(hval,4), h5=__shfl(hval,5);
      float h6=__shfl(hval,6), h7=__shfl(hval,7), h8=__shfl(hval,8);
      float h9=__shfl(hval,9), h10=__shfl(hval,10), h11=__shfl(hval,11);
      float a0 = gg + h0*w[0] + h4*w[4] + h8*w[8];
      float a1 = h1*w[1] + h5*w[5] + h9*w[9];
      float a2 = h2*w[2] + h6*w[6] + h10*w[10];
      float a3 = h3*w[3] + h7*w[7] + h11*w[11];
      float dot = (a0+a1)+(a2+a3);
      float act = amul*frcp(1.f + __expf(negs*dot)) + aadd;
      float ai = __shfl(act, u);
      float af = __shfl(act, u+12);
      float ag = __shfl(act, u+24);
      float ao = __shfl(act, u+36);
      float cn = af*cval + ai*ag;
      float th = 2.f*frcp(1.f + __expf(-2.f*cn)) - 1.f;
      hval = ao*th; cval = cn;
      if (lane < 12) y0[t*24 + d*12 + lane] = hval;
    }
  }
  __syncthreads();

  #pragma unroll
  for (int r = 0; r < 6; ++r){
    int row = tid + r*1024;
    int d = row / 3072; int rem = row - d*3072;
    int t = rem / 48; int j = rem - t*48;
    const float* xr = y0 + t*24;
    const float* wr = w1 + (d*GATES + j)*25;
    float a0=0.f, a1=0.f;
    #pragma unroll
    for (int c=0; c<24; c+=2){ a0 += xr[c]*wr[c]; a1 += xr[c+1]*wr[c+1]; }
    gbuf[(d*TT + t)*GATES + j] = bsum[96 + d*GATES+j] + a0 + a1;
  }
  __syncthreads();

  if (wave < 2){
    int d = wave;
    int j = (lane < GATES) ? lane : (lane - GATES);
    int u = j % 12; int grp = j / 12;
    float w[12];
    const float* wb = whh1 + (d*GATES + j)*12;
    #pragma unroll
    for (int m=0;m<12;++m) w[m] = wb[m];
    float negs  = (grp==2) ? -2.f : -1.f;
    float amul  = (grp==2) ?  2.f :  1.f;
    float aadd  = (grp==2) ? -1.f :  0.f;
    const float* gb = gbuf + d*TT*GATES + j;
    float hval = 0.f, cval = 0.f;
    int t0 = d ? (TT-1) : 0;
    float gnext = gb[t0*GATES];
    for (int s=0;s<TT;++s){
      int t = d ? (TT-1-s) : s;
      float gg = gnext;
      int tn = d ? max(TT-2-s,0) : min(s+1,TT-1);
      gnext = gb[tn*GATES];
      float h0=__shfl(hval,0), h1=__shfl(hval,1), h2=__shfl(hval,2);
      float h3=__shfl(hval,3), h4=__shfl(hval,4), h5=__shfl(hval,5);
      float h6=__shfl(hval,6), h7=__shfl(hval,7), h8=__shfl(hval,8);
      float h9=__shfl(hval,9), h10=__shfl(hval,10), h11=__shfl(hval,11);
      float a0 = gg + h0*w[0] + h4*w[4] + h8*w[8];
      float a1 = h1*w[1] + h5*w[5] + h9*w[9];
      float a2 = h2*w[2] + h6*w[6] + h10*w[10];
      float a3 = h3*w[3] + h7*w[7] + h11*w[11];
      float dot = (a0+a1)+(a2+a3);
      float act = amul*frcp(1.f + __expf(negs*dot)) + aadd;
      float ai = __shfl(act, u);
      float af = __shfl(act, u+12);
      float ag = __shfl(act, u+24);
      float ao = __shfl(act, u+36);
      float cn = af*cval + ai*ag;
      float th = 2.f*frcp(1.f + __expf(-2.f*cn)) - 1.f;
      hval = ao*th; cval = cn;
      if (lane < 12) y1[t*24 + d*12 + lane] = hval;
    }
  }
  __syncthreads();

  for (int idx = tid; idx < TT*72; idx += 1024){
    int gq = idx % 72; int t = idx / 72;
    int p = t*88 + n;
    const float* xr = y1 + t*24;
    const float* wr = sqkv + gq*25;
    float a0=0.f, a1=0.f;
    #pragma unroll
    for (int c=0; c<24; c+=2){ a0 += xr[c]*wr[c]; a1 += xr[c+1]*wr[c+1]; }
    float acc = qkv_b[gq] + a0 + a1;
    int s = gq/24, rem = gq - s*24;
    if (s==0) q[p*24+rem] = acc*0.4082482904638631f;   // 1/sqrt(HD)
    else {
      int hh = rem/6, pos = rem - hh*6;
      bf16* dst = (s==1) ? kh : vh;
      dst[((size_t)hh*NPIX + p)*8 + pos] = __float2bfloat16(acc);
    }
  }
}

// ============ D2: attn layer 1, per-pixel all-heads + fused proj+qkv =======
// (R7 exact structure — est 45 us, absorbs the proj_qkv dispatch)
__global__ __launch_bounds__(256) void k_attn1(
    const float* __restrict__ q, const bf16* __restrict__ kh,
    const bf16* __restrict__ vh, const float* __restrict__ rpb,
    const float* __restrict__ pw, const float* __restrict__ pb,
    const float* __restrict__ qkv_w, const float* __restrict__ qkv_b,
    float* __restrict__ q2, bf16* __restrict__ kh2, bf16* __restrict__ vh2){
  int p = blockIdx.x; int tid = threadIdx.x;
  int h = tid >> 6; int lane = tid & 63;
  int i = p / 88, j = p - i*88;
  int si = min(max(i-12,0),39), sj = min(max(j-12,0),63);
  __shared__ float aorow[24];
  __shared__ float xrow[24];

  float qv[6];
  #pragma unroll
  for (int d=0; d<6; ++d) qv[d] = q[p*24 + h*6 + d];
  const uint4* kb = (const uint4*)(kh + (size_t)h*NPIX*8);
  const uint4* vb = (const uint4*)(vh + (size_t)h*NPIX*8);
  float lgv[10]; int roff[10];
  float lmax = -1e30f;
  #pragma unroll
  for (int it=0; it<10; ++it){
    int nb = lane + it*64;
    bool valid = nb < 625;
    int nbc = valid ? nb : 624;
    int a = nbc/25, cc = nbc - a*25;
    int gi = si + a, gj = sj + cc;
    int row = gi*88+gj;
    roff[it] = row;
    float kr[6];
    unpack6(kb[row], kr);
    float lg = qv[0]*kr[0]+qv[1]*kr[1]+qv[2]*kr[2]+qv[3]*kr[3]+qv[4]*kr[4]+qv[5]*kr[5];
    lg += rpb[(h*49 + (gi - i + 24))*49 + (gj - j + 24)];
    lg = valid ? lg : -1e30f;
    lgv[it] = lg;
    lmax = fmaxf(lmax, lg);
  }
  #pragma unroll
  for (int off=32; off; off>>=1) lmax = fmaxf(lmax, __shfl_xor(lmax, off));
  float lsum = 0.f;
  #pragma unroll
  for (int it=0; it<10; ++it){
    float pe = __expf(lgv[it]-lmax);
    lgv[it] = pe; lsum += pe;
  }
  #pragma unroll
  for (int off=32; off; off>>=1) lsum += __shfl_xor(lsum, off);
  float acc[6] = {0,0,0,0,0,0};
  #pragma unroll
  for (int it=0; it<10; ++it){
    float vr[6];
    unpack6(vb[roff[it]], vr);
    float pe = lgv[it];
    #pragma unroll
    for (int d=0; d<6; ++d) acc[d] += pe*vr[d];
  }
  #pragma unroll
  for (int d=0; d<6; ++d){
    #pragma unroll
    for (int off=32; off; off>>=1) acc[d] += __shfl_xor(acc[d], off);
  }
  if (lane == 0){
    float inv = frcp(lsum);
    #pragma unroll
    for (int d=0; d<6; ++d) aorow[h*6+d] = acc[d]*inv;
  }
  __syncthreads();

  if (tid < 24){
    float a2 = pb[tid];
    const float* wr = pw + tid*24;
    #pragma unroll
    for (int c=0;c<24;++c) a2 += aorow[c]*wr[c];
    xrow[tid] = a2;
  }
  __syncthreads();

  if (tid < 72){
    float a2 = qkv_b[tid];
    const float* wr = qkv_w + tid*24;
    #pragma unroll
    for (int c=0;c<24;++c) a2 += xrow[c]*wr[c];
    int s = tid/24, rem = tid - s*24;
    if (s==0) q2[p*24+rem] = a2*0.4082482904638631f;
    else {
      int hh = rem/6, pos = rem - hh*6;
      bf16* dst = (s==1) ? kh2 : vh2;
      dst[((size_t)hh*NPIX + p)*8 + pos] = __float2bfloat16(a2);
    }
  }
}

// ============ D3: attn layer 2, tiled LDS (R14 exact — ~36 us) =============
__global__ __launch_bounds__(512) void k_attn(
    const float* __restrict__ q, const bf16* __restrict__ kh,
    const bf16* __restrict__ vh, const float* __restrict__ rpb,
    float* __restrict__ ao){
  int b = blockIdx.x;
  int h = b / 704; int rem = b - h*704;
  int ti = rem / 44, tj = rem - ti*44;
  int i0 = ti*4, j0 = tj*2;
  int tid = threadIdx.x;
  int w = tid >> 6; int lane = tid & 63;
  int osi = min(max(i0-12,0),39);
  int osj = min(max(j0-12,0),63);

  __shared__ unsigned kt[728*5];    // row stride 5 uints (coprime w/ 32 banks)
  __shared__ unsigned vt[728*5];
  const uint4* kg = (const uint4*)(kh + (size_t)h*NPIX*8);
  const uint4* vg = (const uint4*)(vh + (size_t)h*NPIX*8);
  for (int idx = tid; idx < 728; idx += 512){
    int a = idx / 26, cc = idx - a*26;
    int gi = min(osi + a, 63), gj = min(osj + cc, 87);
    int src = gi*88 + gj;
    uint4 kr = kg[src];
    uint4 vr = vg[src];
    int o = idx*5;
    kt[o] = kr.x; kt[o+1] = kr.y; kt[o+2] = kr.z;
    vt[o] = vr.x; vt[o+1] = vr.y; vt[o+2] = vr.z;
  }
  __syncthreads();

  int pi = i0 + (w>>1), pj = j0 + (w&1);
  int p = pi*88 + pj;
  int dsi = min(max(pi-12,0),39) - osi;
  int dsj = min(max(pj-12,0),63) - osj;
  int rbi = osi + dsi - pi + 24;
  int rbj = osj + dsj - pj + 24;

  float qv[6];
  #pragma unroll
  for (int d=0; d<6; ++d) qv[d] = q[p*24 + h*6 + d];

  float lgv[10]; int rof[10];
  float lmax = -1e30f;
  #pragma unroll
  for (int it=0; it<10; ++it){
    int nb = lane + it*64;
    bool valid = nb < 625;
    int nbc = valid ? nb : 624;
    int a = nbc/25, cc = nbc - a*25;
    int r5 = ((a+dsi)*26 + (cc+dsj))*5;
    rof[it] = r5;
    unsigned k0 = kt[r5], k1 = kt[r5+1], k2 = kt[r5+2];
    float lg = qv[0]*blo(k0)+qv[1]*bhi(k0)+qv[2]*blo(k1)
             + qv[3]*bhi(k1)+qv[4]*blo(k2)+qv[5]*bhi(k2);
    lg += rpb[(h*49 + (a + rbi))*49 + (cc + rbj)];
    lg = valid ? lg : -1e30f;
    lgv[it] = lg;
    lmax = fmaxf(lmax, lg);
  }
  #pragma unroll
  for (int off=32; off; off>>=1) lmax = fmaxf(lmax, __shfl_xor(lmax, off));
  float lsum = 0.f;
  #pragma unroll
  for (int it=0; it<10; ++it){
    float pe = __expf(lgv[it]-lmax);
    lgv[it] = pe; lsum += pe;
  }
  #pragma unroll
  for (int off=32; off; off>>=1) lsum += __shfl_xor(lsum, off);
  float acc[6] = {0,0,0,0,0,0};
  #pragma unroll
  for (int it=0; it<10; ++it){
    int r5 = rof[it];
    unsigned v0 = vt[r5], v1 = vt[r5+1], v2 = vt[r5+2];
    float pe = lgv[it];
    acc[0] += pe*blo(v0); acc[1] += pe*bhi(v0);
    acc[2] += pe*blo(v1); acc[3] += pe*bhi(v1);
    acc[4] += pe*blo(v2); acc[5] += pe*bhi(v2);
  }
  #pragma unroll
  for (int d=0; d<6; ++d){
    #pragma unroll
    for (int off=32; off; off>>=1) acc[d] += __shfl_xor(acc[d], off);
  }
  if (lane == 0){
    float inv = frcp(lsum);
    #pragma unroll
    for (int d=0; d<6; ++d) ao[p*24 + h*6 + d] = acc[d]*inv;
  }
}

// ============ D4: proj + final 24->5 head (R14 exact) ======================
__global__ __launch_bounds__(64) void k_proj_out(const float* __restrict__ ain,
    const float* __restrict__ pw, const float* __restrict__ pb,
    const float* __restrict__ ow, const float* __restrict__ ob,
    float* __restrict__ out){
  int p = blockIdx.x; int tid = threadIdx.x;
  __shared__ float arow[24];
  __shared__ float xrow[24];
  if (tid < 24) arow[tid] = ain[p*24+tid];
  __syncthreads();
  if (tid < 24){
    float a2 = pb[tid];
    const float* wr = pw + tid*24;
    #pragma unroll
    for (int c=0;c<24;++c) a2 += arow[c]*wr[c];
    xrow[tid] = a2;
  }
  __syncthreads();
  if (tid < 5){
    float a2 = ob[tid];
    const float* wr = ow + tid*24;
    #pragma unroll
    for (int c=0;c<24;++c) a2 += xrow[c]*wr[c];
    out[p*5+tid] = a2;
  }
}

extern "C" void kernel_launch(void* const* d_in, const int* in_sizes, int n_in,
                              void* d_out, int out_size, void* d_ws, size_t ws_size,
                              hipStream_t stream) {
  const float* feat    = (const float*)d_in[0];
  const int*   cond    = (const int*)  d_in[1];
  const float* mask    = (const float*)d_in[2];
  const float* emb     = (const float*)d_in[3];
  const float* w_ih_l0 = (const float*)d_in[4];
  const float* w_hh_l0 = (const float*)d_in[5];
  const float* b_ih_l0 = (const float*)d_in[6];
  const float* b_hh_l0 = (const float*)d_in[7];
  const float* w_ih_l1 = (const float*)d_in[8];
  const float* w_hh_l1 = (const float*)d_in[9];
  const float* b_ih_l1 = (const float*)d_in[10];
  const float* b_hh_l1 = (const float*)d_in[11];
  const float* qkv_w   = (const float*)d_in[12];
  const float* qkv_b   = (const float*)d_in[13];
  const float* rpb     = (const float*)d_in[14];
  const float* proj_w  = (const float*)d_in[15];
  const float* proj_b  = (const float*)d_in[16];
  const float* out_w   = (const float*)d_in[17];
  const float* out_b   = (const float*)d_in[18];
  float* out = (float*)d_out;

  float* ws  = (float*)d_ws;
  float* Q1  = ws;                    // 135168 floats
  float* Q2  = Q1 + 135168;           // 135168
  float* AO  = Q2 + 135168;           // 135168
  bf16*  KH1 = (bf16*)(AO + 135168);  // 180224 halves each
  bf16*  VH1 = KH1 + 180224;
  bf16*  KH2 = VH1 + 180224;
  bf16*  VH2 = KH2 + 180224;

  k_core<<<NSEQ, 1024, 0, stream>>>(
      feat, cond, mask, emb,
      w_ih_l0, w_hh_l0, b_ih_l0, b_hh_l0,
      w_ih_l1, w_hh_l1, b_ih_l1, b_hh_l1,
      qkv_w, qkv_b, Q1, KH1, VH1);

  k_attn1<<<NPIX, 256, 0, stream>>>(
      Q1, KH1, VH1, rpb, proj_w, proj_b, qkv_w, qkv_b,
      Q2, KH2, VH2);

  k_attn<<<4*16*44, 512, 0, stream>>>(Q2, KH2, VH2, rpb, AO);

  k_proj_out<<<NPIX, 64, 0, stream>>>(AO, proj_w, proj_b, out_w, out_b, out);
}